// Round 16
// baseline (109.027 us; speedup 1.0000x reference)
//
#include <hip/hip_runtime.h>

#define N_TOK 8192

typedef _Float16 f16x8 __attribute__((ext_vector_type(8)));
typedef _Float16 f16x4 __attribute__((ext_vector_type(4)));
typedef float    f32x4 __attribute__((ext_vector_type(4)));

__device__ __forceinline__ f32x4 mfma_k32(f16x8 a, f16x8 b, f32x4 c) {
  return __builtin_amdgcn_mfma_f32_16x16x32_f16(a, b, c, 0, 0, 0);
}
// Legacy K=16 MFMA: B-frag layout B[k=quad*4+b][col=l15] matches the K=32
// C layout (rows quad*4+r in regs) exactly -> P feeds PV with NO transpose.
__device__ __forceinline__ f32x4 mfma_k16(f16x4 a, f16x4 b, f32x4 c) {
  return __builtin_amdgcn_mfma_f32_16x16x16f16(a, b, c, 0, 0, 0);
}

// QSCALE^2 = log2(e)/sqrt(32); fold softmax scale + ln->log2 into q so
// s2[n,m] = qe_n . qe_m is directly the exp2 exponent.
#define QSCALE 0.50500977f

// ---------------------------------------------------------------------------
// Kernel A (prep): 256 blocks x 1024 thr; block b owns n-slice n0=b*32.
// Emits qe slice, blocked vht slice, seeds out with x, zeroes Ln.
// vht[nblk][c][inner32]: inner pos = q*8+h*4+r for n_local = h*16+q*4+r;
// a lane's f16x8 at inner q*8 holds the two K=16 PV A-frags.
// ---------------------------------------------------------------------------
__global__ __launch_bounds__(1024) void prep_kernel(
    const float* __restrict__ x, const float* __restrict__ W,
    const float* __restrict__ bias, _Float16* __restrict__ qe,
    _Float16* __restrict__ vht, float* __restrict__ Ln,
    float* __restrict__ out) {
  __shared__ float Wl[32 * 65];
  __shared__ float xl[64 * 36];
  int t = threadIdx.x, b = blockIdx.x;
  int n0 = b * 32;
  if (b < 8) Ln[b * 1024 + t] = 0.f;  // zero softmax-denominator accum
  for (int i = t; i < 2048; i += 1024) Wl[(i >> 6) * 65 + (i & 63)] = W[i];
  if (t < 512) {
    int c = t >> 3, j4 = t & 7;  // j4 = n_local/4
    f32x4 v = *(const f32x4*)(x + c * N_TOK + n0 + j4 * 4);
    *(f32x4*)&xl[c * 36 + j4 * 4] = v;
    *(f32x4*)(out + c * N_TOK + n0 + j4 * 4) = v;  // seed out = x
    f16x4 hv;
#pragma unroll
    for (int j = 0; j < 4; ++j) hv[j] = (_Float16)v[j];
    int q = j4 & 3, h = j4 >> 2;
    *(f16x4*)(vht + b * 2048 + c * 32 + q * 8 + h * 4) = hv;
  }
  __syncthreads();
  int nl = t >> 5, o = t & 31;
  float a0 = bias[o], a1 = 0.f;
#pragma unroll
  for (int c = 0; c < 32; ++c) {
    a0 = fmaf(Wl[o * 65 + c], xl[c * 36 + nl], a0);
    a1 = fmaf(Wl[o * 65 + 32 + c], xl[(32 + c) * 36 + nl], a1);
  }
  qe[(n0 + nl) * 32 + o] = (_Float16)((a0 + a1) * QSCALE);
}

// ---------------------------------------------------------------------------
// Kernel B (pass 1): Ln[n] += sum_{m in m-QUARTER} exp2(qe_n . qe_m)
// 512 blocks = 128 row-tiles (64 n) x 4 m-quarters; 16 waves split the
// 2048-m quarter 16 ways (128 m each). LDS 4KB + ~50 VGPR -> 2 blocks/CU
// co-resident (32 waves/CU); the old 256-block grid left the second block
// slot empty (1 block/CU = 16 waves). Partial row-sums are exp-space
// additive -> unsafeAtomicAdd merges across quarters.
// ---------------------------------------------------------------------------
__global__ __launch_bounds__(1024) void pass1_kernel(
    const _Float16* __restrict__ qe, float* __restrict__ Ln) {
  __shared__ float Lp[16][64];
  int t = threadIdx.x, b = blockIdx.x;
  int w = t >> 6, lane = t & 63, quad = lane >> 4, l15 = lane & 15;
  int n0 = (b >> 2) * 64;
  int mbase = (b & 3) * 2048 + w * 128;
  f16x8 af[4];
#pragma unroll
  for (int g = 0; g < 4; ++g)
    af[g] = *(const f16x8*)(qe + (n0 + g * 16 + l15) * 32 + quad * 8);
  f32x4 sums[4];
#pragma unroll
  for (int g = 0; g < 4; ++g) sums[g] = f32x4{0.f, 0.f, 0.f, 0.f};
  for (int mt = 0; mt < 4; ++mt) {
    int m0 = mbase + mt * 32;
    f16x8 bf0 = *(const f16x8*)(qe + (m0 + l15) * 32 + quad * 8);
    f16x8 bf1 = *(const f16x8*)(qe + (m0 + 16 + l15) * 32 + quad * 8);
    f32x4 zero = {0.f, 0.f, 0.f, 0.f};
#pragma unroll
    for (int g = 0; g < 4; ++g) {
      f32x4 s0 = mfma_k32(af[g], bf0, zero);  // rows n0+g*16+quad*4+r
      f32x4 s1 = mfma_k32(af[g], bf1, zero);
#pragma unroll
      for (int r = 0; r < 4; ++r)
        sums[g][r] +=
            __builtin_amdgcn_exp2f(s0[r]) + __builtin_amdgcn_exp2f(s1[r]);
    }
  }
  // reduce across the 16 m-columns (l15 = lane bits 0..3)
#pragma unroll
  for (int g = 0; g < 4; ++g)
#pragma unroll
    for (int r = 0; r < 4; ++r)
#pragma unroll
      for (int mask = 1; mask < 16; mask <<= 1)
        sums[g][r] += __shfl_xor(sums[g][r], mask, 64);
  if (l15 == 0) {
#pragma unroll
    for (int g = 0; g < 4; ++g)
      *(f32x4*)&Lp[w][g * 16 + quad * 4] = sums[g];
  }
  __syncthreads();
  if (t < 64) {
    float L = 0.f;
#pragma unroll
    for (int ww = 0; ww < 16; ++ww) L += Lp[ww][t];
    unsafeAtomicAdd(Ln + n0 + t, L);
  }
}

// ---------------------------------------------------------------------------
// Kernel C (pass 2): out[c,m] += sum_{n in half} vh[c,n]*exp2(s_nm - Bn[n])
// ROUND-9 EXACT (session best, 99.4us): 256 blocks = 128 m-tiles (64 m) x
// 2 n-halves. 16 waves = 8 n-segs x 2 m-halves; each wave owns all 64 c.
// acc[4ct][2mt] = 32 VGPR -- fits the backend's hard 64-VGPR cap for
// 1024-thr kernels (r11-r14: 64-acc spills 90MB regardless of coding).
// Duplication triangle: traffic-dup (this) beats exp2-dup (r6) and
// no-dup-but-spill (r11-14); 2x-occupancy variant (r15) was neutral.
// Bl = -log2(Ln) in LDS, fed as MFMA C-operand (free subtract).
// ---------------------------------------------------------------------------
__global__ __launch_bounds__(1024, 4) void pass2_kernel(
    const _Float16* __restrict__ qe, const _Float16* __restrict__ vht,
    const float* __restrict__ Ln, float* __restrict__ out) {
  __shared__ float Bl[4096];         // -log2(Ln) for this n-half
  __shared__ float Ot[4 * 64 * 65];  // combine: [4 sets][64 c][65 m]
  int t = threadIdx.x, b = blockIdx.x;
  int w = t >> 6, lane = t & 63, quad = lane >> 4, l15 = lane & 15;
  int m0 = (b >> 1) * 64;  // 64-m tile
  int half = b & 1;        // n-half
  int nseg = w >> 1, mhalf = w & 1;
  int nhb = half * 4096, nbl0 = nseg * 512;

  // Bl once per block (plain loads: pass1->pass2 kernel boundary makes the
  // Ln atomics visible; verified rounds 5-15).
  for (int i = t; i < 4096; i += 1024)
    Bl[i] = -__builtin_amdgcn_logf(Ln[nhb + i]);  // v_log_f32 = log2
  __syncthreads();

  // B frags: this wave's 32 m-columns (mhalf half of the 64-m tile)
  f16x8 bm[2];
#pragma unroll
  for (int mt = 0; mt < 2; ++mt)
    bm[mt] =
        *(const f16x8*)(qe + (m0 + mhalf * 32 + mt * 16 + l15) * 32 + quad * 8);

  f32x4 acc[4][2];
#pragma unroll
  for (int ct = 0; ct < 4; ++ct)
#pragma unroll
    for (int mt = 0; mt < 2; ++mt) acc[ct][mt] = f32x4{0.f, 0.f, 0.f, 0.f};

  for (int ch = 0; ch < 16; ++ch) {
    int nbl = nbl0 + ch * 32;
    int nb = nhb + nbl;
    f16x8 an0 = *(const f16x8*)(qe + (nb + l15) * 32 + quad * 8);
    f16x8 an1 = *(const f16x8*)(qe + (nb + 16 + l15) * 32 + quad * 8);
    f32x4 nBq0 = *(const f32x4*)&Bl[nbl + quad * 4];
    f32x4 nBq1 = *(const f32x4*)&Bl[nbl + 16 + quad * 4];
    const _Float16* vb = vht + (nb >> 5) * 2048 + l15 * 32 + quad * 8;
    f16x8 av[4];
#pragma unroll
    for (int ct = 0; ct < 4; ++ct)
      av[ct] = *(const f16x8*)(vb + ct * 512);  // c = ct*16 + l15
#pragma unroll
    for (int mt = 0; mt < 2; ++mt) {
      // C = -Bn: MFMA emits s - Bn directly.
      f32x4 s0 = mfma_k32(an0, bm[mt], nBq0);  // n=nb+quad*4+r
      f32x4 s1 = mfma_k32(an1, bm[mt], nBq1);  // n=nb+16+quad*4+r
      f16x4 p0, p1;
#pragma unroll
      for (int r = 0; r < 4; ++r) {
        p0[r] = (_Float16)__builtin_amdgcn_exp2f(s0[r]);
        p1[r] = (_Float16)__builtin_amdgcn_exp2f(s1[r]);
      }
#pragma unroll
      for (int ct = 0; ct < 4; ++ct) {
        f16x4 lo, hi;
#pragma unroll
        for (int j = 0; j < 4; ++j) {
          lo[j] = av[ct][j];
          hi[j] = av[ct][j + 4];
        }
        acc[ct][mt] = mfma_k16(lo, p0, acc[ct][mt]);
        acc[ct][mt] = mfma_k16(hi, p1, acc[ct][mt]);
      }
    }
  }

  // Combine partials across 8 n-segments (8 -> 4 -> 1), then atomic out.
  // mhalf pairs write disjoint m-columns; sets indexed by nseg.
  __syncthreads();
  if (nseg < 4) {
#pragma unroll
    for (int ct = 0; ct < 4; ++ct)
#pragma unroll
      for (int mt = 0; mt < 2; ++mt)
#pragma unroll
        for (int r = 0; r < 4; ++r)
          Ot[(nseg * 64 + ct * 16 + quad * 4 + r) * 65 + mhalf * 32 +
             mt * 16 + l15] = acc[ct][mt][r];
  }
  __syncthreads();
  if (nseg >= 4) {
#pragma unroll
    for (int ct = 0; ct < 4; ++ct)
#pragma unroll
      for (int mt = 0; mt < 2; ++mt)
#pragma unroll
        for (int r = 0; r < 4; ++r)
          Ot[((nseg - 4) * 64 + ct * 16 + quad * 4 + r) * 65 + mhalf * 32 +
             mt * 16 + l15] += acc[ct][mt][r];
  }
  __syncthreads();
  // 4096 outputs, 1024 threads -> 4 each; m consecutive across lanes.
  for (int idx = t; idx < 4096; idx += 1024) {
    int cc = idx >> 6, m = idx & 63;
    float v = 0.f;
#pragma unroll
    for (int s = 0; s < 4; ++s) v += Ot[(s * 64 + cc) * 65 + m];
    unsafeAtomicAdd(out + cc * N_TOK + m0 + m, v);
  }
}

// ---------------------------------------------------------------------------
extern "C" void kernel_launch(void* const* d_in, const int* in_sizes, int n_in,
                              void* d_out, int out_size, void* d_ws,
                              size_t ws_size, hipStream_t stream) {
  const float* x = (const float*)d_in[0];     // [64][8192]
  const float* W = (const float*)d_in[1];     // [32][64]
  const float* bias = (const float*)d_in[2];  // [32]
  float* out = (float*)d_out;                 // [64][8192]

  char* ws = (char*)d_ws;
  _Float16* qe = (_Float16*)ws;              // 8192*32*2 = 512 KB
  _Float16* vht = (_Float16*)(ws + 524288);  // blocked vh: 1 MB
  float* Ln = (float*)(ws + 1572864);        // 8192*4 = 32 KB

  prep_kernel<<<256, 1024, 0, stream>>>(x, W, bias, qe, vht, Ln, out);
  pass1_kernel<<<512, 1024, 0, stream>>>(qe, Ln);
  pass2_kernel<<<256, 1024, 0, stream>>>(qe, vht, Ln, out);
}

// Round 17
// 99.777 us; speedup vs baseline: 1.0927x; 1.0927x over previous
//
#include <hip/hip_runtime.h>

#define N_TOK 8192

typedef _Float16 f16x8 __attribute__((ext_vector_type(8)));
typedef _Float16 f16x4 __attribute__((ext_vector_type(4)));
typedef float    f32x4 __attribute__((ext_vector_type(4)));

__device__ __forceinline__ f32x4 mfma_k32(f16x8 a, f16x8 b, f32x4 c) {
  return __builtin_amdgcn_mfma_f32_16x16x32_f16(a, b, c, 0, 0, 0);
}
// Legacy K=16 MFMA: B-frag layout B[k=quad*4+b][col=l15] matches the K=32
// C layout (rows quad*4+r in regs) exactly -> P feeds PV with NO transpose.
__device__ __forceinline__ f32x4 mfma_k16(f16x4 a, f16x4 b, f32x4 c) {
  return __builtin_amdgcn_mfma_f32_16x16x16f16(a, b, c, 0, 0, 0);
}

// QSCALE^2 = log2(e)/sqrt(32); fold softmax scale + ln->log2 into q so
// s2[n,m] = qe_n . qe_m is directly the exp2 exponent.
#define QSCALE 0.50500977f

// ---------------------------------------------------------------------------
// Kernel A (prep): 256 blocks x 1024 thr; block b owns n-slice n0=b*32.
// Emits qe slice, blocked vht slice, seeds out with x, zeroes Ln.
// vht[nblk][c][inner32]: inner pos = q*8+h*4+r for n_local = h*16+q*4+r;
// a lane's f16x8 at inner q*8 holds the two K=16 PV A-frags.
// ---------------------------------------------------------------------------
__global__ __launch_bounds__(1024) void prep_kernel(
    const float* __restrict__ x, const float* __restrict__ W,
    const float* __restrict__ bias, _Float16* __restrict__ qe,
    _Float16* __restrict__ vht, float* __restrict__ Ln,
    float* __restrict__ out) {
  __shared__ float Wl[32 * 65];
  __shared__ float xl[64 * 36];
  int t = threadIdx.x, b = blockIdx.x;
  int n0 = b * 32;
  if (b < 8) Ln[b * 1024 + t] = 0.f;  // zero softmax-denominator accum
  for (int i = t; i < 2048; i += 1024) Wl[(i >> 6) * 65 + (i & 63)] = W[i];
  if (t < 512) {
    int c = t >> 3, j4 = t & 7;  // j4 = n_local/4
    f32x4 v = *(const f32x4*)(x + c * N_TOK + n0 + j4 * 4);
    *(f32x4*)&xl[c * 36 + j4 * 4] = v;
    *(f32x4*)(out + c * N_TOK + n0 + j4 * 4) = v;  // seed out = x
    f16x4 hv;
#pragma unroll
    for (int j = 0; j < 4; ++j) hv[j] = (_Float16)v[j];
    int q = j4 & 3, h = j4 >> 2;
    *(f16x4*)(vht + b * 2048 + c * 32 + q * 8 + h * 4) = hv;
  }
  __syncthreads();
  int nl = t >> 5, o = t & 31;
  float a0 = bias[o], a1 = 0.f;
#pragma unroll
  for (int c = 0; c < 32; ++c) {
    a0 = fmaf(Wl[o * 65 + c], xl[c * 36 + nl], a0);
    a1 = fmaf(Wl[o * 65 + 32 + c], xl[(32 + c) * 36 + nl], a1);
  }
  qe[(n0 + nl) * 32 + o] = (_Float16)((a0 + a1) * QSCALE);
}

// ---------------------------------------------------------------------------
// Kernel B (pass 1): Ln[n] += sum_{m in m-half} exp2(qe_n . qe_m)
// 256 blocks = 128 row-tiles (64 n) x 2 m-halves; 16 waves split the 4096-m
// half 16 ways (256 m each). ROUND-9 EXACT: the 512-block quarter variant
// (r16) regressed ~6us -- with only 4 main-loop iters the per-block fixed
// cost (reduction+epilogue+ramp) dominates and is duplicated 2x.
// Partial row-sums are exp-space additive -> unsafeAtomicAdd.
// ---------------------------------------------------------------------------
__global__ __launch_bounds__(1024) void pass1_kernel(
    const _Float16* __restrict__ qe, float* __restrict__ Ln) {
  __shared__ float Lp[16][64];
  int t = threadIdx.x, b = blockIdx.x;
  int w = t >> 6, lane = t & 63, quad = lane >> 4, l15 = lane & 15;
  int n0 = (b >> 1) * 64;
  int mbase = (b & 1) * 4096 + w * 256;
  f16x8 af[4];
#pragma unroll
  for (int g = 0; g < 4; ++g)
    af[g] = *(const f16x8*)(qe + (n0 + g * 16 + l15) * 32 + quad * 8);
  f32x4 sums[4];
#pragma unroll
  for (int g = 0; g < 4; ++g) sums[g] = f32x4{0.f, 0.f, 0.f, 0.f};
  for (int mt = 0; mt < 8; ++mt) {
    int m0 = mbase + mt * 32;
    f16x8 bf0 = *(const f16x8*)(qe + (m0 + l15) * 32 + quad * 8);
    f16x8 bf1 = *(const f16x8*)(qe + (m0 + 16 + l15) * 32 + quad * 8);
    f32x4 zero = {0.f, 0.f, 0.f, 0.f};
#pragma unroll
    for (int g = 0; g < 4; ++g) {
      f32x4 s0 = mfma_k32(af[g], bf0, zero);  // rows n0+g*16+quad*4+r
      f32x4 s1 = mfma_k32(af[g], bf1, zero);
#pragma unroll
      for (int r = 0; r < 4; ++r)
        sums[g][r] +=
            __builtin_amdgcn_exp2f(s0[r]) + __builtin_amdgcn_exp2f(s1[r]);
    }
  }
  // reduce across the 16 m-columns (l15 = lane bits 0..3)
#pragma unroll
  for (int g = 0; g < 4; ++g)
#pragma unroll
    for (int r = 0; r < 4; ++r)
#pragma unroll
      for (int mask = 1; mask < 16; mask <<= 1)
        sums[g][r] += __shfl_xor(sums[g][r], mask, 64);
  if (l15 == 0) {
#pragma unroll
    for (int g = 0; g < 4; ++g)
      *(f32x4*)&Lp[w][g * 16 + quad * 4] = sums[g];
  }
  __syncthreads();
  if (t < 64) {
    float L = 0.f;
#pragma unroll
    for (int ww = 0; ww < 16; ++ww) L += Lp[ww][t];
    unsafeAtomicAdd(Ln + n0 + t, L);
  }
}

// ---------------------------------------------------------------------------
// Kernel C (pass 2): out[c,m] += sum_{n in half} vh[c,n]*exp2(s_nm - Bn[n])
// ROUND-9 EXACT (session best, 99.4us): 256 blocks = 128 m-tiles (64 m) x
// 2 n-halves. 16 waves = 8 n-segs x 2 m-halves; each wave owns all 64 c.
// acc[4ct][2mt] = 32 VGPR -- fits the backend's hard 64-VGPR cap for
// 1024-thr kernels (r11-r14: 64-acc spills 90MB regardless of coding).
// Duplication triangle: traffic-dup (this) beats exp2-dup (r6) and
// no-dup-but-spill (r11-14); occupancy-2x variants neutral/worse (r15/r16).
// Bl = -log2(Ln) in LDS, fed as MFMA C-operand (free subtract).
// ---------------------------------------------------------------------------
__global__ __launch_bounds__(1024, 4) void pass2_kernel(
    const _Float16* __restrict__ qe, const _Float16* __restrict__ vht,
    const float* __restrict__ Ln, float* __restrict__ out) {
  __shared__ float Bl[4096];         // -log2(Ln) for this n-half
  __shared__ float Ot[4 * 64 * 65];  // combine: [4 sets][64 c][65 m]
  int t = threadIdx.x, b = blockIdx.x;
  int w = t >> 6, lane = t & 63, quad = lane >> 4, l15 = lane & 15;
  int m0 = (b >> 1) * 64;  // 64-m tile
  int half = b & 1;        // n-half
  int nseg = w >> 1, mhalf = w & 1;
  int nhb = half * 4096, nbl0 = nseg * 512;

  // Bl once per block (plain loads: pass1->pass2 kernel boundary makes the
  // Ln atomics visible; verified rounds 5-16).
  for (int i = t; i < 4096; i += 1024)
    Bl[i] = -__builtin_amdgcn_logf(Ln[nhb + i]);  // v_log_f32 = log2
  __syncthreads();

  // B frags: this wave's 32 m-columns (mhalf half of the 64-m tile)
  f16x8 bm[2];
#pragma unroll
  for (int mt = 0; mt < 2; ++mt)
    bm[mt] =
        *(const f16x8*)(qe + (m0 + mhalf * 32 + mt * 16 + l15) * 32 + quad * 8);

  f32x4 acc[4][2];
#pragma unroll
  for (int ct = 0; ct < 4; ++ct)
#pragma unroll
    for (int mt = 0; mt < 2; ++mt) acc[ct][mt] = f32x4{0.f, 0.f, 0.f, 0.f};

  for (int ch = 0; ch < 16; ++ch) {
    int nbl = nbl0 + ch * 32;
    int nb = nhb + nbl;
    f16x8 an0 = *(const f16x8*)(qe + (nb + l15) * 32 + quad * 8);
    f16x8 an1 = *(const f16x8*)(qe + (nb + 16 + l15) * 32 + quad * 8);
    f32x4 nBq0 = *(const f32x4*)&Bl[nbl + quad * 4];
    f32x4 nBq1 = *(const f32x4*)&Bl[nbl + 16 + quad * 4];
    const _Float16* vb = vht + (nb >> 5) * 2048 + l15 * 32 + quad * 8;
    f16x8 av[4];
#pragma unroll
    for (int ct = 0; ct < 4; ++ct)
      av[ct] = *(const f16x8*)(vb + ct * 512);  // c = ct*16 + l15
#pragma unroll
    for (int mt = 0; mt < 2; ++mt) {
      // C = -Bn: MFMA emits s - Bn directly.
      f32x4 s0 = mfma_k32(an0, bm[mt], nBq0);  // n=nb+quad*4+r
      f32x4 s1 = mfma_k32(an1, bm[mt], nBq1);  // n=nb+16+quad*4+r
      f16x4 p0, p1;
#pragma unroll
      for (int r = 0; r < 4; ++r) {
        p0[r] = (_Float16)__builtin_amdgcn_exp2f(s0[r]);
        p1[r] = (_Float16)__builtin_amdgcn_exp2f(s1[r]);
      }
#pragma unroll
      for (int ct = 0; ct < 4; ++ct) {
        f16x4 lo, hi;
#pragma unroll
        for (int j = 0; j < 4; ++j) {
          lo[j] = av[ct][j];
          hi[j] = av[ct][j + 4];
        }
        acc[ct][mt] = mfma_k16(lo, p0, acc[ct][mt]);
        acc[ct][mt] = mfma_k16(hi, p1, acc[ct][mt]);
      }
    }
  }

  // Combine partials across 8 n-segments (8 -> 4 -> 1), then atomic out.
  // mhalf pairs write disjoint m-columns; sets indexed by nseg.
  __syncthreads();
  if (nseg < 4) {
#pragma unroll
    for (int ct = 0; ct < 4; ++ct)
#pragma unroll
      for (int mt = 0; mt < 2; ++mt)
#pragma unroll
        for (int r = 0; r < 4; ++r)
          Ot[(nseg * 64 + ct * 16 + quad * 4 + r) * 65 + mhalf * 32 +
             mt * 16 + l15] = acc[ct][mt][r];
  }
  __syncthreads();
  if (nseg >= 4) {
#pragma unroll
    for (int ct = 0; ct < 4; ++ct)
#pragma unroll
      for (int mt = 0; mt < 2; ++mt)
#pragma unroll
        for (int r = 0; r < 4; ++r)
          Ot[((nseg - 4) * 64 + ct * 16 + quad * 4 + r) * 65 + mhalf * 32 +
             mt * 16 + l15] += acc[ct][mt][r];
  }
  __syncthreads();
  // 4096 outputs, 1024 threads -> 4 each; m consecutive across lanes.
  for (int idx = t; idx < 4096; idx += 1024) {
    int cc = idx >> 6, m = idx & 63;
    float v = 0.f;
#pragma unroll
    for (int s = 0; s < 4; ++s) v += Ot[(s * 64 + cc) * 65 + m];
    unsafeAtomicAdd(out + cc * N_TOK + m0 + m, v);
  }
}

// ---------------------------------------------------------------------------
extern "C" void kernel_launch(void* const* d_in, const int* in_sizes, int n_in,
                              void* d_out, int out_size, void* d_ws,
                              size_t ws_size, hipStream_t stream) {
  const float* x = (const float*)d_in[0];     // [64][8192]
  const float* W = (const float*)d_in[1];     // [32][64]
  const float* bias = (const float*)d_in[2];  // [32]
  float* out = (float*)d_out;                 // [64][8192]

  char* ws = (char*)d_ws;
  _Float16* qe = (_Float16*)ws;              // 8192*32*2 = 512 KB
  _Float16* vht = (_Float16*)(ws + 524288);  // blocked vh: 1 MB
  float* Ln = (float*)(ws + 1572864);        // 8192*4 = 32 KB

  prep_kernel<<<256, 1024, 0, stream>>>(x, W, bias, qe, vht, Ln, out);
  pass1_kernel<<<256, 1024, 0, stream>>>(qe, Ln);
  pass2_kernel<<<256, 1024, 0, stream>>>(qe, vht, Ln, out);
}